// Round 5
// baseline (1705.708 us; speedup 1.0000x reference)
//
#include <hip/hip_runtime.h>
#include <math.h>

// Problem constants
#define Bsz 16
#define Nn  1024
#define Ee  128
#define CTX 384
#define DIN 768
#define DST 16
#define DTR 24
#define ROWS (Bsz*Nn)   // 16384

// ---------------------------------------------------------------------------
// RMS row scales over the virtual ctx = [graph_emb(256) | node_emb(128)]
// ---------------------------------------------------------------------------
__global__ __launch_bounds__(128) void rms_k(
    const float* __restrict__ ge, const float* __restrict__ ne,
    float* __restrict__ rs)
{
    int row = blockIdx.x;            // b*1024 + n
    int b = row >> 10;
    int tid = threadIdx.x;
    float ssq = 0.f;
    #pragma unroll
    for (int k = 0; k < 3; ++k) {
        int idx = tid + k * 128;
        float v = (idx < 256) ? ge[b * 256 + idx]
                              : ne[(long long)row * 128 + (idx - 256)];
        ssq += v * v;
    }
    __shared__ float sh[128];
    sh[tid] = ssq;
    __syncthreads();
    for (int w = 64; w > 0; w >>= 1) {
        if (tid < w) sh[tid] += sh[tid + w];
        __syncthreads();
    }
    if (tid == 0) rs[row] = rsqrtf(sh[0] * (1.f / 384.f) + 1e-6f);
}

__global__ __launch_bounds__(256) void zero_k(float* __restrict__ p, int n)
{
    int i = blockIdx.x * 256 + threadIdx.x;
    if (i < n) p[i] = 0.f;
}

// ---------------------------------------------------------------------------
// gemm2: C[M,N] = A[M,K] @ B[K,N].  128x128 tile, BK=16, 256 thr, 8x8/thread.
// AMODE: 0 = A row-major [m*lda+k]; 1 = A composed from [ge|ne]*rs[m]*rms_w[k];
//        2 = A K-major [k*lda + m] (coalesced float4 along m)
// BT:    false = B row-major [k*ldb+n]; true = B stored [n*ldb+k] (transpose-load)
// CT:    true  = store C transposed: C[gn*ldc + gm] (EPI 0 only)
// EPI:   0 plain; 3 acc+add (batched); 4 acc + ctx residual; 5 softplus(acc+bias[row])
// ---------------------------------------------------------------------------
template<int EPI, bool BT, int AMODE, bool CT>
__global__ __launch_bounds__(256) void gemm2_k(
    const float* __restrict__ A, int lda, long long aB,
    const float* __restrict__ Bm, int ldb, long long bB,
    float* __restrict__ C, int ldc, long long cB,
    int M, int N, int K,
    const float* __restrict__ ge, const float* __restrict__ ne,
    const float* __restrict__ rowS, const float* __restrict__ colS,
    const float* __restrict__ bias,
    const float* __restrict__ add, long long addB)
{
    __shared__ float As[16][132];
    __shared__ float Bs[16][132];
    int t = threadIdx.x;
    int gn0 = blockIdx.x * 128;
    int rowBase = blockIdx.y * 128;
    int bz = blockIdx.z;
    const float* Abase = A + (long long)bz * aB;
    const float* Bb = Bm + (long long)bz * bB;
    float acc[8][8] = {};

    int cx4 = (t & 15) * 4;
    int ry4 = (t >> 4) * 4;

    for (int k0 = 0; k0 < K; k0 += 16) {
        // ---- load A tile -> As[kk][m] ----
        if (AMODE == 0 || AMODE == 1) {
            int r = t >> 1;              // 0..127
            int kq = (t & 1) * 8;        // 0 or 8
            float av[8];
            if (AMODE == 0) {
                const float* Ap = Abase + (long long)(rowBase + r) * lda + k0 + kq;
                #pragma unroll
                for (int j = 0; j < 8; ++j)
                    av[j] = (k0 + kq + j < K) ? Ap[j] : 0.f;
            } else {
                int grow = rowBase + r;
                float rsv = rowS[grow];
                #pragma unroll
                for (int j = 0; j < 8; ++j) {
                    int col = k0 + kq + j;
                    float v = 0.f;
                    if (col < K) {
                        v = (col < 256) ? ge[(grow >> 10) * 256 + col]
                                        : ne[(long long)grow * 128 + (col - 256)];
                        v *= rsv * colS[col];
                    }
                    av[j] = v;
                }
            }
            #pragma unroll
            for (int j = 0; j < 8; ++j) As[kq + j][r] = av[j];
        } else {
            int kk = t >> 4;             // 0..15
            int m0 = (t & 15) * 8;       // 0..120
            const float* Ap = Abase + (long long)(k0 + kk) * lda + rowBase + m0;
            float4 v0 = make_float4(0.f, 0.f, 0.f, 0.f), v1 = v0;
            if (k0 + kk < K) {
                v0 = *(const float4*)Ap;
                v1 = *(const float4*)(Ap + 4);
            }
            *(float4*)&As[kk][m0] = v0;
            *(float4*)&As[kk][m0 + 4] = v1;
        }
        // ---- load B tile -> Bs[kk][n] ----
        if (!BT) {
            int kk = t >> 4;
            int n0 = (t & 15) * 8;
            const float* Bp = Bb + (long long)(k0 + kk) * ldb + gn0 + n0;
            float4 v0 = make_float4(0.f, 0.f, 0.f, 0.f), v1 = v0;
            if (k0 + kk < K) {
                if (gn0 + n0 + 7 < N) {
                    v0 = *(const float4*)Bp;
                    v1 = *(const float4*)(Bp + 4);
                } else {
                    float tmp[8];
                    #pragma unroll
                    for (int j = 0; j < 8; ++j)
                        tmp[j] = (gn0 + n0 + j < N) ? Bp[j] : 0.f;
                    v0 = make_float4(tmp[0], tmp[1], tmp[2], tmp[3]);
                    v1 = make_float4(tmp[4], tmp[5], tmp[6], tmp[7]);
                }
            }
            *(float4*)&Bs[kk][n0] = v0;
            *(float4*)&Bs[kk][n0 + 4] = v1;
        } else {
            int n = t >> 1;
            int kq = (t & 1) * 8;
            const float* Bp = Bb + (long long)(gn0 + n) * ldb + k0 + kq;
            float bv[8];
            bool nok = (gn0 + n < N);
            #pragma unroll
            for (int j = 0; j < 8; ++j)
                bv[j] = (nok && k0 + kq + j < K) ? Bp[j] : 0.f;
            #pragma unroll
            for (int j = 0; j < 8; ++j) Bs[kq + j][n] = bv[j];
        }
        __syncthreads();
        // ---- compute ----
        #pragma unroll
        for (int kk = 0; kk < 16; ++kk) {
            float4 a0 = *(const float4*)&As[kk][ry4];
            float4 a1 = *(const float4*)&As[kk][ry4 + 64];
            float4 b0 = *(const float4*)&Bs[kk][cx4];
            float4 b1 = *(const float4*)&Bs[kk][cx4 + 64];
            float av[8] = {a0.x, a0.y, a0.z, a0.w, a1.x, a1.y, a1.z, a1.w};
            float bv[8] = {b0.x, b0.y, b0.z, b0.w, b1.x, b1.y, b1.z, b1.w};
            #pragma unroll
            for (int i = 0; i < 8; ++i)
                #pragma unroll
                for (int j = 0; j < 8; ++j)
                    acc[i][j] = fmaf(av[i], bv[j], acc[i][j]);
        }
        __syncthreads();
    }

    // ---- epilogue ----
    if (CT) {
        // transposed store (EPI 0): C[gn*ldc + gm]
        #pragma unroll
        for (int j = 0; j < 8; ++j) {
            int gn = gn0 + (j >> 2) * 64 + cx4 + (j & 3);
            #pragma unroll
            for (int ih = 0; ih < 2; ++ih) {
                int gmb = rowBase + ih * 64 + ry4;
                float4 v = make_float4(acc[ih * 4 + 0][j], acc[ih * 4 + 1][j],
                                       acc[ih * 4 + 2][j], acc[ih * 4 + 3][j]);
                *(float4*)&C[(long long)gn * ldc + gmb] = v;
            }
        }
    } else {
        float* Cb = C + (long long)bz * cB;
        #pragma unroll
        for (int i = 0; i < 8; ++i) {
            int gm = rowBase + (i >> 2) * 64 + ry4 + (i & 3);
            #pragma unroll
            for (int jh = 0; jh < 2; ++jh) {
                int gn = gn0 + jh * 64 + cx4;
                float v[4];
                #pragma unroll
                for (int e = 0; e < 4; ++e) {
                    float x = acc[i][jh * 4 + e];
                    if (EPI == 3) {
                        x += add[(long long)bz * addB + (long long)gm * (long long)N + gn + e];
                    } else if (EPI == 4) {
                        int c = gn + e;
                        x += (c < 256) ? ge[(gm >> 10) * 256 + c]
                                       : ne[(long long)gm * 128 + (c - 256)];
                    } else if (EPI == 5) {
                        float s = x + bias[gm];
                        x = fmaxf(s, 0.f) + log1pf(expf(-fabsf(s)));
                    }
                    v[e] = x;
                }
                if (gn + 3 < N) {
                    *(float4*)&Cb[(long long)gm * ldc + gn] =
                        make_float4(v[0], v[1], v[2], v[3]);
                } else {
                    #pragma unroll
                    for (int e = 0; e < 4; ++e)
                        if (gn + e < N) Cb[(long long)gm * ldc + gn + e] = v[e];
                }
            }
        }
    }
}

// ---------------------------------------------------------------------------
// Depthwise causal conv (K=4) + bias + SiLU, writing TRANSPOSED output:
// uT[d][b*1024+n] from uB[(b*1024+n)*768+d]. LDS tile 67x32 (3-row halo).
// ---------------------------------------------------------------------------
__global__ __launch_bounds__(256) void conv_t_k(
    const float* __restrict__ uB, const float* __restrict__ cw,
    const float* __restrict__ cb, float* __restrict__ uT)
{
    __shared__ float tile[67][33];
    int b = blockIdx.z, d0 = blockIdx.y * 32, n0 = blockIdx.x * 64;
    int tid = threadIdx.x;
    for (int i = tid; i < 67 * 32; i += 256) {
        int r = i >> 5, c = i & 31;
        int n = n0 - 3 + r;
        tile[r][c] = (n >= 0) ? uB[((long long)(b * 1024 + n)) * 768 + d0 + c] : 0.f;
    }
    __syncthreads();
    int nl = tid & 63;
    int dh = (tid >> 6) * 8;
    #pragma unroll
    for (int dl = 0; dl < 8; ++dl) {
        int d = dh + dl;
        const float* w = cw + (d0 + d) * 4;
        float acc = cb[d0 + d];
        acc = fmaf(tile[nl][d],     w[0], acc);
        acc = fmaf(tile[nl + 1][d], w[1], acc);
        acc = fmaf(tile[nl + 2][d], w[2], acc);
        acc = fmaf(tile[nl + 3][d], w[3], acc);
        float sv = acc / (1.f + __expf(-acc));
        uT[(long long)(d0 + d) * 16384 + b * 1024 + n0 + nl] = sv;
    }
}

// ---------------------------------------------------------------------------
// S6 scan v4: 4 states per lane, 4 lanes per channel, 4 sequence chunks of 256.
// Block = (16 channels) x (4 sq-lanes) x (4 chunks) = 256 threads.
// Pass 1: chunk-local scan from h0=0, collect h_end + decay product P.
// LDS prefix composes per-chunk h0. Pass 2: re-scan from correct h0, emit
// y = (C·h + Dp*u) * silu(z), written in-place over uT.
// B/C read directly from dbc (cols 24+4sq / 40+4sq, 16B-aligned float4).
// ---------------------------------------------------------------------------
__global__ __launch_bounds__(256, 3) void scan4_k(
    const float* __restrict__ dT, float* uyT, const float* __restrict__ zT,
    const float* __restrict__ dbc, const float* __restrict__ A_log,
    const float* __restrict__ Dp)
{
    __shared__ float sH[4][16][16];
    __shared__ float sP[4][16][16];
    __shared__ float sh0[4][16][16];
    int t = threadIdx.x;
    int ch = t >> 4;            // 0..15  channel within block
    int sq = (t >> 2) & 3;      // 0..3   state quad
    int c  = t & 3;             // 0..3   sequence chunk
    int b = blockIdx.y;
    int d = blockIdx.x * 16 + ch;
    float av[4];
    #pragma unroll
    for (int j = 0; j < 4; ++j) av[j] = -__expf(A_log[d * 16 + 4 * sq + j]);
    float dp = Dp[d];
    long long base = (long long)d * 16384 + b * 1024 + c * 256;
    const float* dR = dT + base;
    const float* uR = uyT + base;
    const float* zR = zT + base;
    float* yR = uyT + base;
    const float* bRow = dbc + (long long)(b * 1024 + c * 256) * 56;

    float hs[4] = {0.f, 0.f, 0.f, 0.f};
    float Ps[4] = {1.f, 1.f, 1.f, 1.f};

    // ---- pass 1: local scan, h_end + P ----
    {
        float4 dv0 = *(const float4*)(dR);
        float4 dv1 = *(const float4*)(dR + 4);
        float4 uv0 = *(const float4*)(uR);
        float4 uv1 = *(const float4*)(uR + 4);
        for (int g = 0; g < 64; ++g) {
            int gp = (g + 2 < 64 ? g + 2 : 63) * 4;
            float4 dv2 = *(const float4*)(dR + gp);
            float4 uv2 = *(const float4*)(uR + gp);
            float dvx[4] = {dv0.x, dv0.y, dv0.z, dv0.w};
            float uvx[4] = {uv0.x, uv0.y, uv0.z, uv0.w};
            const float* br = bRow + (long long)(g * 4) * 56 + 24 + 4 * sq;
            #pragma unroll
            for (int j = 0; j < 4; ++j) {
                float4 Bv = *(const float4*)(br + j * 56);
                float du = dvx[j] * uvx[j];
                float e;
                e = __expf(dvx[j] * av[0]); hs[0] = fmaf(e, hs[0], du * Bv.x); Ps[0] *= e;
                e = __expf(dvx[j] * av[1]); hs[1] = fmaf(e, hs[1], du * Bv.y); Ps[1] *= e;
                e = __expf(dvx[j] * av[2]); hs[2] = fmaf(e, hs[2], du * Bv.z); Ps[2] *= e;
                e = __expf(dvx[j] * av[3]); hs[3] = fmaf(e, hs[3], du * Bv.w); Ps[3] *= e;
            }
            dv0 = dv1; dv1 = dv2; uv0 = uv1; uv1 = uv2;
        }
    }

    // ---- LDS prefix over chunks ----
    #pragma unroll
    for (int j = 0; j < 4; ++j) {
        sH[c][ch][4 * sq + j] = hs[j];
        sP[c][ch][4 * sq + j] = Ps[j];
    }
    __syncthreads();
    {
        int ch2 = t >> 4, s2 = t & 15;
        float hh = 0.f;
        #pragma unroll
        for (int c2 = 0; c2 < 4; ++c2) {
            sh0[c2][ch2][s2] = hh;
            hh = fmaf(sP[c2][ch2][s2], hh, sH[c2][ch2][s2]);
        }
    }
    __syncthreads();
    #pragma unroll
    for (int j = 0; j < 4; ++j) hs[j] = sh0[c][ch][4 * sq + j];

    // ---- pass 2: full scan from correct h0, emit gated y ----
    {
        float4 dv0 = *(const float4*)(dR);
        float4 dv1 = *(const float4*)(dR + 4);
        float4 uv0 = *(const float4*)(uR);
        float4 uv1 = *(const float4*)(uR + 4);
        float4 zv0 = *(const float4*)(zR);
        float4 zv1 = *(const float4*)(zR + 4);
        for (int g = 0; g < 64; ++g) {
            int gp = (g + 2 < 64 ? g + 2 : 63) * 4;
            float4 dv2 = *(const float4*)(dR + gp);
            float4 uv2 = *(const float4*)(uR + gp);
            float4 zv2 = *(const float4*)(zR + gp);
            float dvx[4] = {dv0.x, dv0.y, dv0.z, dv0.w};
            float uvx[4] = {uv0.x, uv0.y, uv0.z, uv0.w};
            float zvx[4] = {zv0.x, zv0.y, zv0.z, zv0.w};
            const float* br = bRow + (long long)(g * 4) * 56 + 24 + 4 * sq;
            float ya[4];
            #pragma unroll
            for (int j = 0; j < 4; ++j) {
                float4 Bv = *(const float4*)(br + j * 56);
                float4 Cv = *(const float4*)(br + j * 56 + 16);
                float du = dvx[j] * uvx[j];
                float e;
                e = __expf(dvx[j] * av[0]); hs[0] = fmaf(e, hs[0], du * Bv.x);
                e = __expf(dvx[j] * av[1]); hs[1] = fmaf(e, hs[1], du * Bv.y);
                e = __expf(dvx[j] * av[2]); hs[2] = fmaf(e, hs[2], du * Bv.z);
                e = __expf(dvx[j] * av[3]); hs[3] = fmaf(e, hs[3], du * Bv.w);
                float yp = hs[0] * Cv.x;
                yp = fmaf(hs[1], Cv.y, yp);
                yp = fmaf(hs[2], Cv.z, yp);
                yp = fmaf(hs[3], Cv.w, yp);
                yp += __shfl_down(yp, 8, 16);
                yp += __shfl_down(yp, 4, 16);
                float z = zvx[j];
                ya[j] = (yp + dp * uvx[j]) * (z / (1.f + __expf(-z)));
            }
            if (sq == 0) {
                *(float4*)(yR + g * 4) = make_float4(ya[0], ya[1], ya[2], ya[3]);
            }
            dv0 = dv1; dv1 = dv2;
            uv0 = uv1; uv1 = uv2;
            zv0 = zv1; zv1 = zv2;
        }
    }
}

// ---------------------------------------------------------------------------
// Sinkhorn half-iterations on la = la0 - R_i - C_j (never materialized).
// ---------------------------------------------------------------------------
__global__ __launch_bounds__(256) void col_lse_part(
    const float* __restrict__ la0, const float* __restrict__ R,
    float2* __restrict__ cpart)
{
    int j = blockIdx.x * 256 + threadIdx.x;
    int ch = blockIdx.y;   // 16 chunks of 64 i's
    int b = blockIdx.z;
    const float* base = la0 + (long long)b * 1024 * 1024 + (long long)ch * 64 * 1024 + j;
    const float* Rb = R + b * 1024 + ch * 64;
    float m = -INFINITY, sum = 0.f;
    for (int i = 0; i < 64; ++i) {
        float x = base[(long long)i * 1024] - Rb[i];
        float nm = fmaxf(m, x);
        sum = sum * expf(m - nm) + expf(x - nm);
        m = nm;
    }
    cpart[(long long)(b * 16 + ch) * 1024 + j] = make_float2(m, sum);
}

__global__ __launch_bounds__(256) void col_comb_k(
    const float2* __restrict__ cpart, float* __restrict__ Cv)
{
    int idx = blockIdx.x * 256 + threadIdx.x;   // b*1024 + j
    int b = idx >> 10, j = idx & 1023;
    float m = -INFINITY, sum = 0.f;
    #pragma unroll
    for (int ch = 0; ch < 16; ++ch) {
        float2 p = cpart[(long long)(b * 16 + ch) * 1024 + j];
        float nm = fmaxf(m, p.x);
        sum = sum * expf(m - nm) + p.y * expf(p.x - nm);
        m = nm;
    }
    Cv[idx] = m + logf(sum);
}

__global__ __launch_bounds__(256) void row_lse_k(
    const float* __restrict__ la0, const float* __restrict__ Cv,
    float* __restrict__ R)
{
    int r = blockIdx.x;
    int b = r >> 10;
    const float* row = la0 + (long long)r * 1024;
    const float* Cb = Cv + b * 1024;
    int tid = threadIdx.x;
    float m = -INFINITY, sum = 0.f;
    #pragma unroll
    for (int k = 0; k < 4; ++k) {
        int j = tid + k * 256;
        float x = row[j] - Cb[j];
        float nm = fmaxf(m, x);
        sum = sum * expf(m - nm) + expf(x - nm);
        m = nm;
    }
    __shared__ float sm[256], ss[256];
    sm[tid] = m; ss[tid] = sum;
    __syncthreads();
    for (int w = 128; w > 0; w >>= 1) {
        if (tid < w) {
            float m2 = sm[tid + w], s2 = ss[tid + w];
            float nm = fmaxf(sm[tid], m2);
            ss[tid] = ss[tid] * expf(sm[tid] - nm) + s2 * expf(m2 - nm);
            sm[tid] = nm;
        }
        __syncthreads();
    }
    if (tid == 0) R[r] = sm[0] + logf(ss[0]);
}

// ---------------------------------------------------------------------------
// Final: argmax(la+gumbel) (first-index ties), log_prob, entropy.
// out layout: tours[16384] | log_probs[16384] | entropies[16384] (all fp32)
// ---------------------------------------------------------------------------
__global__ __launch_bounds__(256) void final_k(
    const float* __restrict__ la0, const float* __restrict__ R,
    const float* __restrict__ Cv, const float* __restrict__ gs,
    float* __restrict__ out)
{
    int r = blockIdx.x;
    int b = r >> 10;
    const float* row = la0 + (long long)r * 1024;
    const float* gr = gs + (long long)r * 1024;
    const float* Cb = Cv + b * 1024;
    float Rvv = R[r];
    int tid = threadIdx.x;
    float bestg = -INFINITY;
    int bestj = 1 << 30;
    float ent = 0.f;
    #pragma unroll
    for (int k = 0; k < 4; ++k) {
        int j = tid + k * 256;
        float la = row[j] - Rvv - Cb[j];
        ent += la * expf(la);
        float g = la + gr[j];
        if (g > bestg || (g == bestg && j < bestj)) { bestg = g; bestj = j; }
    }
    __shared__ float sg[256]; __shared__ int sj[256]; __shared__ float se[256];
    sg[tid] = bestg; sj[tid] = bestj; se[tid] = ent;
    __syncthreads();
    for (int w = 128; w > 0; w >>= 1) {
        if (tid < w) {
            se[tid] += se[tid + w];
            float g2 = sg[tid + w]; int j2 = sj[tid + w];
            if (g2 > sg[tid] || (g2 == sg[tid] && j2 < sj[tid])) {
                sg[tid] = g2; sj[tid] = j2;
            }
        }
        __syncthreads();
    }
    if (tid == 0) {
        int j = sj[0];
        out[r] = (float)j;
        out[16384 + r] = row[j] - Rvv - Cb[j];
        out[32768 + r] = -se[0];
    }
}

// ---------------------------------------------------------------------------
extern "C" void kernel_launch(void* const* d_in, const int* in_sizes, int n_in,
                              void* d_out, int out_size, void* d_ws, size_t ws_size,
                              hipStream_t stream)
{
    const float* graph_emb = (const float*)d_in[0];
    const float* node_emb  = (const float*)d_in[1];
    const float* W_key     = (const float*)d_in[2];
    const float* rms_w     = (const float*)d_in[3];
    const float* W_in      = (const float*)d_in[4];
    const float* conv_w    = (const float*)d_in[5];
    const float* conv_b    = (const float*)d_in[6];
    const float* W_x       = (const float*)d_in[7];
    const float* W_dt      = (const float*)d_in[8];
    const float* b_dt      = (const float*)d_in[9];
    const float* A_log     = (const float*)d_in[10];
    const float* Dp        = (const float*)d_in[11];
    const float* W_out     = (const float*)d_in[12];
    const float* g_sink    = (const float*)d_in[13];
    const float* g_samp    = (const float*)d_in[14];
    float* out = (float*)d_out;

    // Workspace layout (floats). Total = 45,531,136 floats = 182.1 MB.
    float* ws = (float*)d_ws;
    size_t o = 0;
    auto alloc = [&](size_t nf) { float* p = ws + o; o += nf; return p; };
    float* rs    = alloc(ROWS);                    // 16K
    float* dbc   = alloc((size_t)ROWS * 56);       // 0.92M (live through scan)
    float* keys  = alloc((size_t)ROWS * 384);      // 6.29M
    float* R1    = alloc((size_t)ROWS * 768);      // uB -> deltaT -> queries
    float* R2    = alloc((size_t)ROWS * 768);      // uT -> gated yT (in-place); la0 starts here
    float* R3    = alloc((size_t)ROWS * 768);      // zT; la0 spills here
    float* Rv    = alloc(ROWS);
    float* Cvec  = alloc(ROWS);
    float* cpart = alloc((size_t)16 * 16 * 1024 * 2);  // Sinkhorn partials
    float* uB      = R1;
    float* deltaT  = R1;    // uB dead after conv
    float* queries = R1;    // deltaT dead after scan
    float* uT      = R2;    // also gated yT (scan writes in-place)
    float* zT      = R3;
    float* la0     = R2;    // R2+R3 span 25.17M >= 16.78M; yT/zT dead by then

    // 1. RMS row scales over virtual ctx
    rms_k<<<dim3(ROWS), 128, 0, stream>>>(graph_emb, node_emb, rs);

    // 2. keys = node_emb @ W_key       (16384 x 384 x 128)
    gemm2_k<0, false, 0, false><<<dim3(3, 128, 1), 256, 0, stream>>>(
        node_emb, 128, 0, W_key, 384, 0, keys, 384, 0,
        ROWS, 384, 128, nullptr, nullptr, nullptr, nullptr, nullptr, nullptr, 0);

    // 3a. uB = rmsnorm(ctx) @ W_in[:, :768]   (16384 x 768 x 384)
    gemm2_k<0, false, 1, false><<<dim3(6, 128, 1), 256, 0, stream>>>(
        nullptr, 0, 0, W_in, 1536, 0, uB, 768, 0,
        ROWS, 768, 384, graph_emb, node_emb, rs, rms_w, nullptr, nullptr, 0);

    // 3b. zT[768][16384] = (rmsnorm(ctx) @ W_in[:, 768:])^T  (transposed store)
    gemm2_k<0, false, 1, true><<<dim3(6, 128, 1), 256, 0, stream>>>(
        nullptr, 0, 0, W_in + 768, 1536, 0, zT, 16384, 0,
        ROWS, 768, 384, graph_emb, node_emb, rs, rms_w, nullptr, nullptr, 0);

    // 4. causal depthwise conv + silu, transposed out: uT[d][b*1024+n]
    conv_t_k<<<dim3(16, 24, 16), 256, 0, stream>>>(uB, conv_w, conv_b, uT);

    // 5. dbc = u @ W_x  (A = uT, K-major)      (16384 x 56 x 768)
    gemm2_k<0, false, 2, false><<<dim3(1, 128, 1), 256, 0, stream>>>(
        uT, 16384, 0, W_x, 56, 0, dbc, 56, 0,
        ROWS, 56, 768, nullptr, nullptr, nullptr, nullptr, nullptr, nullptr, 0);

    // 6. deltaT[768 x 16384] = softplus(W_dt^T @ dbc_dt^T + b_dt[row])
    gemm2_k<5, true, 2, false><<<dim3(128, 6, 1), 256, 0, stream>>>(
        W_dt, 768, 0, dbc, 56, 0, deltaT, 16384, 0,
        768, 16384, 24, nullptr, nullptr, nullptr, nullptr, b_dt, nullptr, 0);

    // 7. scan v4 (chunked two-pass, 4 states/lane); gated y in-place over uT
    scan4_k<<<dim3(48, 16), 256, 0, stream>>>(deltaT, uT, zT, dbc, A_log, Dp);

    // 8. queries = ctx + yGated @ W_out    (16384 x 384 x 768)
    gemm2_k<4, false, 2, false><<<dim3(3, 128, 1), 256, 0, stream>>>(
        uT, 16384, 0, W_out, 384, 0, queries, 384, 0,
        ROWS, 384, 768, graph_emb, node_emb, nullptr, nullptr, nullptr, nullptr, 0);

    // 9. la0 = keys @ queries^T + gumbel_sink  (batched NT, 16 x 1024x1024x384)
    gemm2_k<3, true, 0, false><<<dim3(8, 8, 16), 256, 0, stream>>>(
        keys, 384, (long long)Nn * 384, queries, 384, (long long)Nn * 384,
        la0, 1024, (long long)Nn * Nn,
        1024, 1024, 384, nullptr, nullptr, nullptr, nullptr, nullptr,
        g_sink, (long long)Nn * Nn);

    // 10. Sinkhorn: la = la0 - R_i - C_j, alternate LSE updates
    zero_k<<<dim3(64), 256, 0, stream>>>(Rv, ROWS);
    for (int it = 0; it < 5; ++it) {
        col_lse_part<<<dim3(4, 16, 16), 256, 0, stream>>>(la0, Rv, (float2*)cpart);
        col_comb_k<<<dim3(64), 256, 0, stream>>>((const float2*)cpart, Cvec);
        row_lse_k<<<dim3(ROWS), 256, 0, stream>>>(la0, Cvec, Rv);
    }

    // 11. outputs
    final_k<<<dim3(ROWS), 256, 0, stream>>>(la0, Rv, Cvec, g_samp, out);
}

// Round 6
// 1505.786 us; speedup vs baseline: 1.1328x; 1.1328x over previous
//
#include <hip/hip_runtime.h>
#include <math.h>

// Problem constants
#define Bsz 16
#define Nn  1024
#define Ee  128
#define CTX 384
#define DIN 768
#define DST 16
#define DTR 24
#define ROWS (Bsz*Nn)   // 16384

typedef __attribute__((ext_vector_type(8))) short short8;
typedef __attribute__((ext_vector_type(4))) float f32x4;

// ---------------------------------------------------------------------------
// RMS row scales over the virtual ctx = [graph_emb(256) | node_emb(128)]
// ---------------------------------------------------------------------------
__global__ __launch_bounds__(128) void rms_k(
    const float* __restrict__ ge, const float* __restrict__ ne,
    float* __restrict__ rs)
{
    int row = blockIdx.x;            // b*1024 + n
    int b = row >> 10;
    int tid = threadIdx.x;
    float ssq = 0.f;
    #pragma unroll
    for (int k = 0; k < 3; ++k) {
        int idx = tid + k * 128;
        float v = (idx < 256) ? ge[b * 256 + idx]
                              : ne[(long long)row * 128 + (idx - 256)];
        ssq += v * v;
    }
    __shared__ float sh[128];
    sh[tid] = ssq;
    __syncthreads();
    for (int w = 64; w > 0; w >>= 1) {
        if (tid < w) sh[tid] += sh[tid + w];
        __syncthreads();
    }
    if (tid == 0) rs[row] = rsqrtf(sh[0] * (1.f / 384.f) + 1e-6f);
}

__global__ __launch_bounds__(256) void zero_k(float* __restrict__ p, int n)
{
    int i = blockIdx.x * 256 + threadIdx.x;
    if (i < n) p[i] = 0.f;
}

// ---------------------------------------------------------------------------
// gemm2: fp32 VALU GEMM (unchanged from round 4). 128x128 tile, 8x8/thread.
// ---------------------------------------------------------------------------
template<int EPI, bool BT, int AMODE, bool CT>
__global__ __launch_bounds__(256) void gemm2_k(
    const float* __restrict__ A, int lda, long long aB,
    const float* __restrict__ Bm, int ldb, long long bB,
    float* __restrict__ C, int ldc, long long cB,
    int M, int N, int K,
    const float* __restrict__ ge, const float* __restrict__ ne,
    const float* __restrict__ rowS, const float* __restrict__ colS,
    const float* __restrict__ bias,
    const float* __restrict__ add, long long addB)
{
    __shared__ float As[16][132];
    __shared__ float Bs[16][132];
    int t = threadIdx.x;
    int gn0 = blockIdx.x * 128;
    int rowBase = blockIdx.y * 128;
    int bz = blockIdx.z;
    const float* Abase = A + (long long)bz * aB;
    const float* Bb = Bm + (long long)bz * bB;
    float acc[8][8] = {};

    int cx4 = (t & 15) * 4;
    int ry4 = (t >> 4) * 4;

    for (int k0 = 0; k0 < K; k0 += 16) {
        if (AMODE == 0 || AMODE == 1) {
            int r = t >> 1;
            int kq = (t & 1) * 8;
            float av[8];
            if (AMODE == 0) {
                const float* Ap = Abase + (long long)(rowBase + r) * lda + k0 + kq;
                #pragma unroll
                for (int j = 0; j < 8; ++j)
                    av[j] = (k0 + kq + j < K) ? Ap[j] : 0.f;
            } else {
                int grow = rowBase + r;
                float rsv = rowS[grow];
                #pragma unroll
                for (int j = 0; j < 8; ++j) {
                    int col = k0 + kq + j;
                    float v = 0.f;
                    if (col < K) {
                        v = (col < 256) ? ge[(grow >> 10) * 256 + col]
                                        : ne[(long long)grow * 128 + (col - 256)];
                        v *= rsv * colS[col];
                    }
                    av[j] = v;
                }
            }
            #pragma unroll
            for (int j = 0; j < 8; ++j) As[kq + j][r] = av[j];
        } else {
            int kk = t >> 4;
            int m0 = (t & 15) * 8;
            const float* Ap = Abase + (long long)(k0 + kk) * lda + rowBase + m0;
            float4 v0 = make_float4(0.f, 0.f, 0.f, 0.f), v1 = v0;
            if (k0 + kk < K) {
                v0 = *(const float4*)Ap;
                v1 = *(const float4*)(Ap + 4);
            }
            *(float4*)&As[kk][m0] = v0;
            *(float4*)&As[kk][m0 + 4] = v1;
        }
        if (!BT) {
            int kk = t >> 4;
            int n0 = (t & 15) * 8;
            const float* Bp = Bb + (long long)(k0 + kk) * ldb + gn0 + n0;
            float4 v0 = make_float4(0.f, 0.f, 0.f, 0.f), v1 = v0;
            if (k0 + kk < K) {
                if (gn0 + n0 + 7 < N) {
                    v0 = *(const float4*)Bp;
                    v1 = *(const float4*)(Bp + 4);
                } else {
                    float tmp[8];
                    #pragma unroll
                    for (int j = 0; j < 8; ++j)
                        tmp[j] = (gn0 + n0 + j < N) ? Bp[j] : 0.f;
                    v0 = make_float4(tmp[0], tmp[1], tmp[2], tmp[3]);
                    v1 = make_float4(tmp[4], tmp[5], tmp[6], tmp[7]);
                }
            }
            *(float4*)&Bs[kk][n0] = v0;
            *(float4*)&Bs[kk][n0 + 4] = v1;
        } else {
            int n = t >> 1;
            int kq = (t & 1) * 8;
            const float* Bp = Bb + (long long)(gn0 + n) * ldb + k0 + kq;
            float bv[8];
            bool nok = (gn0 + n < N);
            #pragma unroll
            for (int j = 0; j < 8; ++j)
                bv[j] = (nok && k0 + kq + j < K) ? Bp[j] : 0.f;
            #pragma unroll
            for (int j = 0; j < 8; ++j) Bs[kq + j][n] = bv[j];
        }
        __syncthreads();
        #pragma unroll
        for (int kk = 0; kk < 16; ++kk) {
            float4 a0 = *(const float4*)&As[kk][ry4];
            float4 a1 = *(const float4*)&As[kk][ry4 + 64];
            float4 b0 = *(const float4*)&Bs[kk][cx4];
            float4 b1 = *(const float4*)&Bs[kk][cx4 + 64];
            float av[8] = {a0.x, a0.y, a0.z, a0.w, a1.x, a1.y, a1.z, a1.w};
            float bv[8] = {b0.x, b0.y, b0.z, b0.w, b1.x, b1.y, b1.z, b1.w};
            #pragma unroll
            for (int i = 0; i < 8; ++i)
                #pragma unroll
                for (int j = 0; j < 8; ++j)
                    acc[i][j] = fmaf(av[i], bv[j], acc[i][j]);
        }
        __syncthreads();
    }

    if (CT) {
        #pragma unroll
        for (int j = 0; j < 8; ++j) {
            int gn = gn0 + (j >> 2) * 64 + cx4 + (j & 3);
            #pragma unroll
            for (int ih = 0; ih < 2; ++ih) {
                int gmb = rowBase + ih * 64 + ry4;
                float4 v = make_float4(acc[ih * 4 + 0][j], acc[ih * 4 + 1][j],
                                       acc[ih * 4 + 2][j], acc[ih * 4 + 3][j]);
                *(float4*)&C[(long long)gn * ldc + gmb] = v;
            }
        }
    } else {
        float* Cb = C + (long long)bz * cB;
        #pragma unroll
        for (int i = 0; i < 8; ++i) {
            int gm = rowBase + (i >> 2) * 64 + ry4 + (i & 3);
            #pragma unroll
            for (int jh = 0; jh < 2; ++jh) {
                int gn = gn0 + jh * 64 + cx4;
                float v[4];
                #pragma unroll
                for (int e = 0; e < 4; ++e) {
                    float x = acc[i][jh * 4 + e];
                    if (EPI == 3) {
                        x += add[(long long)bz * addB + (long long)gm * (long long)N + gn + e];
                    } else if (EPI == 4) {
                        int c = gn + e;
                        x += (c < 256) ? ge[(gm >> 10) * 256 + c]
                                       : ne[(long long)gm * 128 + (c - 256)];
                    } else if (EPI == 5) {
                        float s = x + bias[gm];
                        x = fmaxf(s, 0.f) + log1pf(expf(-fabsf(s)));
                    }
                    v[e] = x;
                }
                if (gn + 3 < N) {
                    *(float4*)&Cb[(long long)gm * ldc + gn] =
                        make_float4(v[0], v[1], v[2], v[3]);
                } else {
                    #pragma unroll
                    for (int e = 0; e < 4; ++e)
                        if (gn + e < N) Cb[(long long)gm * ldc + gn + e] = v[e];
                }
            }
        }
    }
}

// ---------------------------------------------------------------------------
// bf16x6 MFMA GEMM for logits: la0 = keys @ queries^T + gumbel_sink (batched).
// Each fp32 split into 3 bf16 (h trunc, m trunc, l rne); K expanded 6x with
// A'=[h,h,m,h,m,l], B'=[h,m,h,l,m,h] -> hh+hm+mh+hl+mm+lh. Dropped terms
// ~2^-23 rel -> logits err ~5e-7 << min Gumbel top-2 gap (~6e-5).
// 128x128 tile, 4 waves x (4x4) mfma_f32_16x16x32_bf16 tiles, 16 real k/step.
// ---------------------------------------------------------------------------
#define MG_LDK 104   // padded LDS row (halves); 208 B, 16B-aligned

__device__ inline void split3(float v, ushort& h, ushort& m, ushort& l)
{
    unsigned u = __float_as_uint(v);
    h = (ushort)(u >> 16);
    float vh = __uint_as_float((unsigned)h << 16);
    float r = v - vh;
    unsigned ur = __float_as_uint(r);
    m = (ushort)(ur >> 16);
    float vm = __uint_as_float((unsigned)m << 16);
    float r2 = r - vm;
    unsigned u2 = __float_as_uint(r2);
    u2 += 0x7fffu + ((u2 >> 16) & 1u);
    l = (ushort)(u2 >> 16);
}

__global__ __launch_bounds__(256) void mgemm_logits_k(
    const float* __restrict__ keys, const float* __restrict__ queries,
    const float* __restrict__ gsink, float* __restrict__ la0)
{
    __shared__ ushort As[128][MG_LDK];
    __shared__ ushort Bs[128][MG_LDK];
    int t = threadIdx.x;
    int n0 = blockIdx.x * 128, m0 = blockIdx.y * 128, bz = blockIdx.z;
    const float* Ag = keys    + ((long long)(bz * 1024 + m0)) * 384;
    const float* Bg = queries + ((long long)(bz * 1024 + n0)) * 384;
    int wave = t >> 6, lane = t & 63;
    int wm = (wave & 1) * 64, wn = (wave >> 1) * 64;
    int lm = lane & 15, lq = lane >> 4;
    f32x4 acc[4][4] = {};   // [m-tile][n-tile]

    for (int kc = 0; kc < 384; kc += 16) {
        // ---- stage + split: threads 0..127 -> A rows, 128..255 -> B rows ----
        {
            int r = t & 127;
            bool isA = (t < 128);
            const float* src = (isA ? Ag : Bg) + (long long)r * 384 + kc;
            #pragma unroll
            for (int q = 0; q < 4; ++q) {
                float4 v = *(const float4*)(src + q * 4);
                float vv[4] = {v.x, v.y, v.z, v.w};
                ushort buf[24];
                #pragma unroll
                for (int e = 0; e < 4; ++e) {
                    ushort h, m, l;
                    split3(vv[e], h, m, l);
                    if (isA) {
                        buf[e*6+0] = h; buf[e*6+1] = h; buf[e*6+2] = m;
                        buf[e*6+3] = h; buf[e*6+4] = m; buf[e*6+5] = l;
                    } else {
                        buf[e*6+0] = h; buf[e*6+1] = m; buf[e*6+2] = h;
                        buf[e*6+3] = l; buf[e*6+4] = m; buf[e*6+5] = h;
                    }
                }
                ushort* dst = (isA ? &As[r][0] : &Bs[r][0]) + q * 24;
                #pragma unroll
                for (int w8 = 0; w8 < 3; ++w8)
                    *(short8*)(dst + w8 * 8) = *(const short8*)&buf[w8 * 8];
            }
        }
        __syncthreads();
        // ---- compute: 3 MFMA depths of 32 halves ----
        #pragma unroll
        for (int dep = 0; dep < 3; ++dep) {
            short8 af[4], bf[4];
            #pragma unroll
            for (int i = 0; i < 4; ++i)
                af[i] = *(const short8*)&As[wm + i * 16 + lm][dep * 32 + lq * 8];
            #pragma unroll
            for (int j = 0; j < 4; ++j)
                bf[j] = *(const short8*)&Bs[wn + j * 16 + lm][dep * 32 + lq * 8];
            #pragma unroll
            for (int i = 0; i < 4; ++i)
                #pragma unroll
                for (int j = 0; j < 4; ++j)
                    acc[i][j] = __builtin_amdgcn_mfma_f32_16x16x32_bf16(
                        af[i], bf[j], acc[i][j], 0, 0, 0);
        }
        __syncthreads();
    }

    // ---- epilogue: D col=lane&15, row=lq*4+reg; += gumbel_sink ----
    long long obase = (long long)bz * 1024 * 1024;
    #pragma unroll
    for (int i = 0; i < 4; ++i) {
        #pragma unroll
        for (int rg = 0; rg < 4; ++rg) {
            int m = m0 + wm + i * 16 + lq * 4 + rg;
            #pragma unroll
            for (int j = 0; j < 4; ++j) {
                int n = n0 + wn + j * 16 + lm;
                long long off = obase + (long long)m * 1024 + n;
                la0[off] = acc[i][j][rg] + gsink[off];
            }
        }
    }
}

// ---------------------------------------------------------------------------
// Depthwise causal conv (K=4) + bias + SiLU, transposed out: uT[d][b*1024+n]
// ---------------------------------------------------------------------------
__global__ __launch_bounds__(256) void conv_t_k(
    const float* __restrict__ uB, const float* __restrict__ cw,
    const float* __restrict__ cb, float* __restrict__ uT)
{
    __shared__ float tile[67][33];
    int b = blockIdx.z, d0 = blockIdx.y * 32, n0 = blockIdx.x * 64;
    int tid = threadIdx.x;
    for (int i = tid; i < 67 * 32; i += 256) {
        int r = i >> 5, c = i & 31;
        int n = n0 - 3 + r;
        tile[r][c] = (n >= 0) ? uB[((long long)(b * 1024 + n)) * 768 + d0 + c] : 0.f;
    }
    __syncthreads();
    int nl = tid & 63;
    int dh = (tid >> 6) * 8;
    #pragma unroll
    for (int dl = 0; dl < 8; ++dl) {
        int d = dh + dl;
        const float* w = cw + (d0 + d) * 4;
        float acc = cb[d0 + d];
        acc = fmaf(tile[nl][d],     w[0], acc);
        acc = fmaf(tile[nl + 1][d], w[1], acc);
        acc = fmaf(tile[nl + 2][d], w[2], acc);
        acc = fmaf(tile[nl + 3][d], w[3], acc);
        float sv = acc / (1.f + __expf(-acc));
        uT[(long long)(d0 + d) * 16384 + b * 1024 + n0 + nl] = sv;
    }
}

// ---------------------------------------------------------------------------
// Pack B/C columns of dbc into TBC[32][16384]: rows 0..15 = B(s), 16..31 = C(s)
// ---------------------------------------------------------------------------
__global__ __launch_bounds__(256) void pack_bc_k(
    const float* __restrict__ dbc, float* __restrict__ TBC)
{
    int c = blockIdx.y;
    int gm = blockIdx.x * 256 + threadIdx.x;
    TBC[(long long)c * 16384 + gm] = dbc[(long long)gm * 56 + 24 + c];
}

// ---------------------------------------------------------------------------
// S6 scan v3 (round-3 version, 287 us): thread=(b,d,s), 16-lane state groups,
// depth-2 float4 prefetch, gated y written in-place over uT.
// ---------------------------------------------------------------------------
__global__ __launch_bounds__(256) void scan3_k(
    const float* __restrict__ dT, float* uyT, const float* __restrict__ zT,
    const float* __restrict__ TBC, const float* __restrict__ A_log,
    const float* __restrict__ Dp)
{
    int tid = threadIdx.x;
    int s = tid & 15, dl = tid >> 4;
    int b = blockIdx.y;
    int d = blockIdx.x * 16 + dl;
    float a = -__expf(A_log[d * 16 + s]);
    float dp = Dp[d];
    long long base = (long long)b * 1024;
    const float* dR = dT + (long long)d * 16384 + base;
    const float* uR = uyT + (long long)d * 16384 + base;
    const float* zR = zT + (long long)d * 16384 + base;
    const float* BR = TBC + (long long)s * 16384 + base;
    const float* CR = TBC + (long long)(16 + s) * 16384 + base;
    float* yR = uyT + (long long)d * 16384 + base;

    float4 dv0 = *(const float4*)(dR);
    float4 dv1 = *(const float4*)(dR + 4);
    float4 uv0 = *(const float4*)(uR);
    float4 uv1 = *(const float4*)(uR + 4);
    float4 zv0 = *(const float4*)(zR);
    float4 zv1 = *(const float4*)(zR + 4);
    float4 Bv0 = *(const float4*)(BR);
    float4 Bv1 = *(const float4*)(BR + 4);
    float4 Cv0 = *(const float4*)(CR);
    float4 Cv1 = *(const float4*)(CR + 4);
    float h = 0.f;

    for (int g = 0; g < 256; ++g) {
        int gp = (g + 2 < 256) ? (g + 2) * 4 : 255 * 4;
        float4 dv2 = *(const float4*)(dR + gp);
        float4 uv2 = *(const float4*)(uR + gp);
        float4 zv2 = *(const float4*)(zR + gp);
        float4 Bv2 = *(const float4*)(BR + gp);
        float4 Cv2 = *(const float4*)(CR + gp);

        float dv[4] = {dv0.x, dv0.y, dv0.z, dv0.w};
        float uv[4] = {uv0.x, uv0.y, uv0.z, uv0.w};
        float zv[4] = {zv0.x, zv0.y, zv0.z, zv0.w};
        float Bv[4] = {Bv0.x, Bv0.y, Bv0.z, Bv0.w};
        float Cv[4] = {Cv0.x, Cv0.y, Cv0.z, Cv0.w};
        float ya[4];
        #pragma unroll
        for (int j = 0; j < 4; ++j) {
            float dA = __expf(dv[j] * a);
            h = fmaf(dA, h, dv[j] * uv[j] * Bv[j]);
            float yp = h * Cv[j];
            yp += __shfl_down(yp, 8, 16);
            yp += __shfl_down(yp, 4, 16);
            yp += __shfl_down(yp, 2, 16);
            yp += __shfl_down(yp, 1, 16);
            float z = zv[j];
            ya[j] = (yp + dp * uv[j]) * (z / (1.f + __expf(-z)));
        }
        if (s == 0) {
            *(float4*)(yR + g * 4) = make_float4(ya[0], ya[1], ya[2], ya[3]);
        }
        dv0 = dv1; dv1 = dv2;
        uv0 = uv1; uv1 = uv2;
        zv0 = zv1; zv1 = zv2;
        Bv0 = Bv1; Bv1 = Bv2;
        Cv0 = Cv1; Cv1 = Cv2;
    }
}

// ---------------------------------------------------------------------------
// Sinkhorn half-iterations on la = la0 - R_i - C_j (never materialized).
// ---------------------------------------------------------------------------
__global__ __launch_bounds__(256) void col_lse_part(
    const float* __restrict__ la0, const float* __restrict__ R,
    float2* __restrict__ cpart)
{
    int j = blockIdx.x * 256 + threadIdx.x;
    int ch = blockIdx.y;
    int b = blockIdx.z;
    const float* base = la0 + (long long)b * 1024 * 1024 + (long long)ch * 64 * 1024 + j;
    const float* Rb = R + b * 1024 + ch * 64;
    float m = -INFINITY, sum = 0.f;
    for (int i = 0; i < 64; ++i) {
        float x = base[(long long)i * 1024] - Rb[i];
        float nm = fmaxf(m, x);
        sum = sum * expf(m - nm) + expf(x - nm);
        m = nm;
    }
    cpart[(long long)(b * 16 + ch) * 1024 + j] = make_float2(m, sum);
}

__global__ __launch_bounds__(256) void col_comb_k(
    const float2* __restrict__ cpart, float* __restrict__ Cv)
{
    int idx = blockIdx.x * 256 + threadIdx.x;
    int b = idx >> 10, j = idx & 1023;
    float m = -INFINITY, sum = 0.f;
    #pragma unroll
    for (int ch = 0; ch < 16; ++ch) {
        float2 p = cpart[(long long)(b * 16 + ch) * 1024 + j];
        float nm = fmaxf(m, p.x);
        sum = sum * expf(m - nm) + p.y * expf(p.x - nm);
        m = nm;
    }
    Cv[idx] = m + logf(sum);
}

__global__ __launch_bounds__(256) void row_lse_k(
    const float* __restrict__ la0, const float* __restrict__ Cv,
    float* __restrict__ R)
{
    int r = blockIdx.x;
    int b = r >> 10;
    const float* row = la0 + (long long)r * 1024;
    const float* Cb = Cv + b * 1024;
    int tid = threadIdx.x;
    float m = -INFINITY, sum = 0.f;
    #pragma unroll
    for (int k = 0; k < 4; ++k) {
        int j = tid + k * 256;
        float x = row[j] - Cb[j];
        float nm = fmaxf(m, x);
        sum = sum * expf(m - nm) + expf(x - nm);
        m = nm;
    }
    __shared__ float sm[256], ss[256];
    sm[tid] = m; ss[tid] = sum;
    __syncthreads();
    for (int w = 128; w > 0; w >>= 1) {
        if (tid < w) {
            float m2 = sm[tid + w], s2 = ss[tid + w];
            float nm = fmaxf(sm[tid], m2);
            ss[tid] = ss[tid] * expf(sm[tid] - nm) + s2 * expf(m2 - nm);
            sm[tid] = nm;
        }
        __syncthreads();
    }
    if (tid == 0) R[r] = sm[0] + logf(ss[0]);
}

// ---------------------------------------------------------------------------
// Final: argmax(la+gumbel), log_prob, entropy.
// ---------------------------------------------------------------------------
__global__ __launch_bounds__(256) void final_k(
    const float* __restrict__ la0, const float* __restrict__ R,
    const float* __restrict__ Cv, const float* __restrict__ gs,
    float* __restrict__ out)
{
    int r = blockIdx.x;
    int b = r >> 10;
    const float* row = la0 + (long long)r * 1024;
    const float* gr = gs + (long long)r * 1024;
    const float* Cb = Cv + b * 1024;
    float Rvv = R[r];
    int tid = threadIdx.x;
    float bestg = -INFINITY;
    int bestj = 1 << 30;
    float ent = 0.f;
    #pragma unroll
    for (int k = 0; k < 4; ++k) {
        int j = tid + k * 256;
        float la = row[j] - Rvv - Cb[j];
        ent += la * expf(la);
        float g = la + gr[j];
        if (g > bestg || (g == bestg && j < bestj)) { bestg = g; bestj = j; }
    }
    __shared__ float sg[256]; __shared__ int sj[256]; __shared__ float se[256];
    sg[tid] = bestg; sj[tid] = bestj; se[tid] = ent;
    __syncthreads();
    for (int w = 128; w > 0; w >>= 1) {
        if (tid < w) {
            se[tid] += se[tid + w];
            float g2 = sg[tid + w]; int j2 = sj[tid + w];
            if (g2 > sg[tid] || (g2 == sg[tid] && j2 < sj[tid])) {
                sg[tid] = g2; sj[tid] = j2;
            }
        }
        __syncthreads();
    }
    if (tid == 0) {
        int j = sj[0];
        out[r] = (float)j;
        out[16384 + r] = row[j] - Rvv - Cb[j];
        out[32768 + r] = -se[0];
    }
}

// ---------------------------------------------------------------------------
extern "C" void kernel_launch(void* const* d_in, const int* in_sizes, int n_in,
                              void* d_out, int out_size, void* d_ws, size_t ws_size,
                              hipStream_t stream)
{
    const float* graph_emb = (const float*)d_in[0];
    const float* node_emb  = (const float*)d_in[1];
    const float* W_key     = (const float*)d_in[2];
    const float* rms_w     = (const float*)d_in[3];
    const float* W_in      = (const float*)d_in[4];
    const float* conv_w    = (const float*)d_in[5];
    const float* conv_b    = (const float*)d_in[6];
    const float* W_x       = (const float*)d_in[7];
    const float* W_dt      = (const float*)d_in[8];
    const float* b_dt      = (const float*)d_in[9];
    const float* A_log     = (const float*)d_in[10];
    const float* Dp        = (const float*)d_in[11];
    const float* W_out     = (const float*)d_in[12];
    const float* g_sink    = (const float*)d_in[13];
    const float* g_samp    = (const float*)d_in[14];
    float* out = (float*)d_out;

    // Workspace layout (floats). Total = 45,531,136 floats = 182.1 MB.
    float* ws = (float*)d_ws;
    size_t o = 0;
    auto alloc = [&](size_t nf) { float* p = ws + o; o += nf; return p; };
    float* rs    = alloc(ROWS);
    float* dbc   = alloc((size_t)ROWS * 56);
    float* keys  = alloc((size_t)ROWS * 384);
    float* R1    = alloc((size_t)ROWS * 768);      // uB -> deltaT -> queries
    float* R2    = alloc((size_t)ROWS * 768);      // uT -> gated yT (in-place); la0 starts here
    float* R3    = alloc((size_t)ROWS * 768);      // zT; la0 spills here
    float* Rv    = alloc(ROWS);
    float* Cvec  = alloc(ROWS);
    float* cpart = alloc((size_t)16 * 16 * 1024 * 2);  // TBC alias (disjoint lifetime)
    float* uB      = R1;
    float* deltaT  = R1;
    float* queries = R1;
    float* uT      = R2;
    float* zT      = R3;
    float* la0     = R2;    // R2+R3 span 25.17M >= 16.78M
    float* TBC     = cpart;

    // 1. RMS row scales
    rms_k<<<dim3(ROWS), 128, 0, stream>>>(graph_emb, node_emb, rs);

    // 2. keys = node_emb @ W_key       (16384 x 384 x 128)
    gemm2_k<0, false, 0, false><<<dim3(3, 128, 1), 256, 0, stream>>>(
        node_emb, 128, 0, W_key, 384, 0, keys, 384, 0,
        ROWS, 384, 128, nullptr, nullptr, nullptr, nullptr, nullptr, nullptr, 0);

    // 3a. uB = rmsnorm(ctx) @ W_in[:, :768]
    gemm2_k<0, false, 1, false><<<dim3(6, 128, 1), 256, 0, stream>>>(
        nullptr, 0, 0, W_in, 1536, 0, uB, 768, 0,
        ROWS, 768, 384, graph_emb, node_emb, rs, rms_w, nullptr, nullptr, 0);

    // 3b. zT = (rmsnorm(ctx) @ W_in[:, 768:])^T
    gemm2_k<0, false, 1, true><<<dim3(6, 128, 1), 256, 0, stream>>>(
        nullptr, 0, 0, W_in + 768, 1536, 0, zT, 16384, 0,
        ROWS, 768, 384, graph_emb, node_emb, rs, rms_w, nullptr, nullptr, 0);

    // 4. conv + silu -> uT
    conv_t_k<<<dim3(16, 24, 16), 256, 0, stream>>>(uB, conv_w, conv_b, uT);

    // 5. dbc = u @ W_x (A = uT, K-major)
    gemm2_k<0, false, 2, false><<<dim3(1, 128, 1), 256, 0, stream>>>(
        uT, 16384, 0, W_x, 56, 0, dbc, 56, 0,
        ROWS, 56, 768, nullptr, nullptr, nullptr, nullptr, nullptr, nullptr, 0);

    // 6. deltaT = softplus(W_dt^T @ dbc_dt^T + b_dt[row])
    gemm2_k<5, true, 2, false><<<dim3(128, 6, 1), 256, 0, stream>>>(
        W_dt, 768, 0, dbc, 56, 0, deltaT, 16384, 0,
        768, 16384, 24, nullptr, nullptr, nullptr, nullptr, b_dt, nullptr, 0);

    // 7. pack B/C into TBC
    pack_bc_k<<<dim3(64, 32), 256, 0, stream>>>(dbc, TBC);

    // 8. scan v3; gated y in-place over uT
    scan3_k<<<dim3(48, 16), 256, 0, stream>>>(deltaT, uT, zT, TBC, A_log, Dp);

    // 9. queries = ctx + yGated @ W_out
    gemm2_k<4, false, 2, false><<<dim3(3, 128, 1), 256, 0, stream>>>(
        uT, 16384, 0, W_out, 384, 0, queries, 384, 0,
        ROWS, 384, 768, graph_emb, node_emb, nullptr, nullptr, nullptr, nullptr, 0);

    // 10. la0 = keys @ queries^T + gumbel_sink  -- bf16x6 MFMA
    mgemm_logits_k<<<dim3(8, 8, 16), 256, 0, stream>>>(keys, queries, g_sink, la0);

    // 11. Sinkhorn
    zero_k<<<dim3(64), 256, 0, stream>>>(Rv, ROWS);
    for (int it = 0; it < 5; ++it) {
        col_lse_part<<<dim3(4, 16, 16), 256, 0, stream>>>(la0, Rv, (float2*)cpart);
        col_comb_k<<<dim3(64), 256, 0, stream>>>((const float2*)cpart, Cvec);
        row_lse_k<<<dim3(ROWS), 256, 0, stream>>>(la0, Cvec, Rv);
    }

    // 12. outputs
    final_k<<<dim3(ROWS), 256, 0, stream>>>(la0, Rv, Cvec, g_samp, out);
}